// Round 1
// baseline (82.477 us; speedup 1.0000x reference)
//
#include <hip/hip_runtime.h>
#include <hip/hip_bf16.h>

// Sizes (fixed by the problem)
#define NS   4096      // samples
#define NV   256       // variables/channels
#define NHID 64        // hidden
#define NCOL 16384     // NV*NHID
// GEMM tiling
#define BM 128
#define BN 128
#define BK 64

typedef short s8v __attribute__((ext_vector_type(8)));
typedef float f4v __attribute__((ext_vector_type(4)));

typedef __attribute__((address_space(1))) const unsigned int GU;
typedef __attribute__((address_space(3))) unsigned int LU;

__device__ __forceinline__ void gload16(const void* gp, void* lp) {
    __builtin_amdgcn_global_load_lds((GU*)gp, (LU*)lp, 16, 0, 0);
}

__device__ __forceinline__ unsigned short f2bf(float x) {
    __hip_bfloat16 h = __float2bfloat16(x);
    return *reinterpret_cast<unsigned short*>(&h);
}

__device__ __forceinline__ float tanh_fast(float x) {
    // tanh(x) = 1 - 2/(exp(2x)+1); saturates correctly for |x| large.
    float e = __expf(2.0f * x);
    return 1.0f - 2.0f * __builtin_amdgcn_rcpf(e + 1.0f);
}

// ---- prep: data f32 -> bf16 ----
__global__ __launch_bounds__(256) void k_prep_data(const float* __restrict__ data,
                                                   unsigned short* __restrict__ dataB) {
    int i = blockIdx.x * 256 + threadIdx.x;          // 262144 float4's
    float4 v = reinterpret_cast<const float4*>(data)[i];
    ushort4 o = make_ushort4(f2bf(v.x), f2bf(v.y), f2bf(v.z), f2bf(v.w));
    reinterpret_cast<ushort4*>(dataB)[i] = o;
}

// ---- prep: W2t[col][k] = adj[k,c] * w_in[c, k-(k>c), h],  col = c*64+h ----
__global__ __launch_bounds__(256) void k_prep_w2t(const float* __restrict__ adj,
                                                  const float* __restrict__ w_in,
                                                  unsigned short* __restrict__ W2t) {
    __shared__ float t[64][65];
    int c  = blockIdx.x >> 2;
    int k0 = (blockIdx.x & 3) * 64;
    int tid = threadIdx.x;
#pragma unroll
    for (int i = 0; i < 16; ++i) {
        int lin = i * 256 + tid;
        int kr = lin >> 6, h = lin & 63;
        int k = k0 + kr;
        float v = 0.0f;
        if (k != c) {
            int m = k - (k > c ? 1 : 0);
            v = adj[k * NV + c] * w_in[((size_t)c * 255 + m) * 64 + h];
        }
        t[kr][h] = v;
    }
    __syncthreads();
#pragma unroll
    for (int i = 0; i < 16; ++i) {
        int lin = i * 256 + tid;
        int h = lin >> 6, kr = lin & 63;
        W2t[((size_t)(c * 64 + h)) * NV + k0 + kr] = f2bf(t[kr][h]);
    }
}

// ---- prep: out0 = adj copy (f32), g[c*64+h] = neurons[h,c]*w_out[c*64+h] ----
__global__ __launch_bounds__(256) void k_misc(const float* __restrict__ adj,
                                              const float* __restrict__ neurons,
                                              const float* __restrict__ w_out,
                                              float* __restrict__ out0,
                                              float* __restrict__ g) {
    int i = blockIdx.x * 256 + threadIdx.x;          // 81920 total
    if (i < NV * NV) {
        out0[i] = adj[i];
    } else {
        int j = i - NV * NV;
        int c = j >> 6, h = j & 63;
        g[j] = neurons[h * NV + c] * w_out[j];
    }
}

// ---- main: GEMM (4096 x 256) x (256 x 16384) + fused tanh/gate/reduce ----
__global__ __launch_bounds__(256) void k_gemm_fused(
        const unsigned short* __restrict__ dataB,   // [4096][256] bf16
        const unsigned short* __restrict__ W2t,     // [16384][256] bf16 (col-major wrt GEMM B)
        const float* __restrict__ g,                // [16384]
        const float* __restrict__ b_in,             // [16384] (V x NH)
        const float* __restrict__ b_out,            // [256]
        float* __restrict__ out1)                   // [4096][256]
{
    __shared__ __align__(16) char lds[32768];       // A: [0,16K)  B: [16K,32K)
    const int tid  = threadIdx.x;
    const int w    = tid >> 6;
    const int lane = tid & 63;
    const int bm0  = (int)(blockIdx.x & 31) * BM;
    const int bn0  = (int)(blockIdx.x >> 5) * BN;
    const int wr   = w >> 1, wc = w & 1;

    f4v acc[4][4];
#pragma unroll
    for (int mi = 0; mi < 4; ++mi)
#pragma unroll
        for (int ni = 0; ni < 4; ++ni)
            acc[mi][ni] = (f4v){0.f, 0.f, 0.f, 0.f};

    // Staging offsets. LDS dest stays LINEAR (global_load_lds constraint);
    // the XOR swizzle is applied to the GLOBAL source + again on ds_read (rule #21).
    unsigned int offA[4], offB[4], ldso[4];
#pragma unroll
    for (int t = 0; t < 4; ++t) {
        int o = w * 4096 + t * 1024 + lane * 16;    // linear byte offset in 16KB tile
        int row = o >> 7;                            // 128 B per row (64 bf16)
        int inner = (o & 127) ^ ((row & 7) << 4);    // inverse swizzle on source
        ldso[t] = (unsigned)(w * 4096 + t * 1024);   // wave-uniform LDS base
        offA[t] = (unsigned)(bm0 + row) * 512u + (unsigned)inner;
        offB[t] = (unsigned)(bn0 + row) * 512u + (unsigned)inner;
    }

    const char* dA = (const char*)dataB;
    const char* dB = (const char*)W2t;

    for (int kt = 0; kt < 4; ++kt) {
#pragma unroll
        for (int t = 0; t < 4; ++t)
            gload16(dA + (size_t)offA[t] + kt * 128, lds + ldso[t]);
#pragma unroll
        for (int t = 0; t < 4; ++t)
            gload16(dB + (size_t)offB[t] + kt * 128, lds + 16384 + ldso[t]);
        __syncthreads();   // compiler drains vmcnt before s_barrier

#pragma unroll
        for (int kk = 0; kk < 2; ++kk) {
            s8v afr[4], bfr[4];
#pragma unroll
            for (int mi = 0; mi < 4; ++mi) {
                int ml = wr * 64 + mi * 16 + (lane & 15);
                int inner = (kk * 64 + ((lane >> 4) << 4)) ^ ((ml & 7) << 4);
                afr[mi] = *reinterpret_cast<const s8v*>(lds + ml * 128 + inner);
            }
#pragma unroll
            for (int ni = 0; ni < 4; ++ni) {
                int nl = wc * 64 + ni * 16 + (lane & 15);
                int inner = (kk * 64 + ((lane >> 4) << 4)) ^ ((nl & 7) << 4);
                bfr[ni] = *reinterpret_cast<const s8v*>(lds + 16384 + nl * 128 + inner);
            }
#pragma unroll
            for (int mi = 0; mi < 4; ++mi)
#pragma unroll
                for (int ni = 0; ni < 4; ++ni)
                    acc[mi][ni] = __builtin_amdgcn_mfma_f32_16x16x32_bf16(
                        afr[mi], bfr[ni], acc[mi][ni], 0, 0, 0);
        }
        __syncthreads();
    }

    // Epilogue: out[n,c] = b_out[c] + sum_h tanh(pre + b_in) * g
    // C/D layout: col = lane&15, row = (lane>>4)*4 + reg   [m89-verified]
    const int cidx = (bn0 >> 6) + wc;                // this wave's channel c
    float gr[4], bi[4];
#pragma unroll
    for (int ni = 0; ni < 4; ++ni) {
        int col = bn0 + wc * 64 + ni * 16 + (lane & 15);
        gr[ni] = g[col];
        bi[ni] = b_in[col];
    }
    const float bo = b_out[cidx];
#pragma unroll
    for (int mi = 0; mi < 4; ++mi) {
#pragma unroll
        for (int r = 0; r < 4; ++r) {
            float s = 0.f;
#pragma unroll
            for (int ni = 0; ni < 4; ++ni)
                s += tanh_fast(acc[mi][ni][r] + bi[ni]) * gr[ni];
            // reduce over the 16 lanes holding this row's 16 columns (x4 ni = 64 h)
            s += __shfl_xor(s, 1);
            s += __shfl_xor(s, 2);
            s += __shfl_xor(s, 4);
            s += __shfl_xor(s, 8);
            if ((lane & 15) == 0) {
                int m = bm0 + wr * 64 + mi * 16 + ((lane >> 4) << 2) + r;
                out1[m * NV + cidx] = s + bo;
            }
        }
    }
}

extern "C" void kernel_launch(void* const* d_in, const int* in_sizes, int n_in,
                              void* d_out, int out_size, void* d_ws, size_t ws_size,
                              hipStream_t stream) {
    const float* data    = (const float*)d_in[0];
    const float* adj     = (const float*)d_in[1];
    const float* neurons = (const float*)d_in[2];
    const float* w_in    = (const float*)d_in[3];
    const float* b_in    = (const float*)d_in[4];
    const float* w_out   = (const float*)d_in[5];
    const float* b_out   = (const float*)d_in[6];

    float* out0 = (float*)d_out;
    float* out1 = out0 + NV * NV;

    unsigned short* dataB = (unsigned short*)d_ws;                       // 2 MiB
    unsigned short* W2t   = (unsigned short*)((char*)d_ws + 2097152);    // 8 MiB
    float*          g     = (float*)((char*)d_ws + 10485760);            // 64 KiB

    hipLaunchKernelGGL(k_prep_data, dim3(1024), dim3(256), 0, stream, data, dataB);
    hipLaunchKernelGGL(k_prep_w2t,  dim3(1024), dim3(256), 0, stream, adj, w_in, W2t);
    hipLaunchKernelGGL(k_misc,      dim3(320),  dim3(256), 0, stream, adj, neurons, w_out, out0, g);
    hipLaunchKernelGGL(k_gemm_fused, dim3(4096), dim3(256), 0, stream,
                       dataB, W2t, g, b_in, b_out, out1);
}

// Round 2
// 80.811 us; speedup vs baseline: 1.0206x; 1.0206x over previous
//
#include <hip/hip_runtime.h>
#include <hip/hip_bf16.h>

// Sizes (fixed by the problem)
#define NS   4096      // samples
#define NV   256       // variables/channels
#define NHID 64        // hidden
#define NCOL 16384     // NV*NHID
// GEMM tiling: 256x256 tile, BK=64, 8 waves (2x4), double-buffered LDS (128 KiB)
#define BM 256
#define BN 256
#define BK 64

typedef short s8v __attribute__((ext_vector_type(8)));
typedef float f4v __attribute__((ext_vector_type(4)));

typedef __attribute__((address_space(1))) const unsigned int GU;
typedef __attribute__((address_space(3))) unsigned int LU;

__device__ __forceinline__ void gload16(const void* gp, void* lp) {
    __builtin_amdgcn_global_load_lds((GU*)gp, (LU*)lp, 16, 0, 0);
}

__device__ __forceinline__ unsigned short f2bf(float x) {
    __hip_bfloat16 h = __float2bfloat16(x);
    return *reinterpret_cast<unsigned short*>(&h);
}

__device__ __forceinline__ float tanh_fast(float x) {
    // tanh(x) = 1 - 2/(exp(2x)+1); saturates correctly for |x| large.
    float e = __expf(2.0f * x);
    return 1.0f - 2.0f * __builtin_amdgcn_rcpf(e + 1.0f);
}

// ---- prep: data f32 -> bf16 ----
__global__ __launch_bounds__(256) void k_prep_data(const float* __restrict__ data,
                                                   unsigned short* __restrict__ dataB) {
    int i = blockIdx.x * 256 + threadIdx.x;          // 262144 float4's
    float4 v = reinterpret_cast<const float4*>(data)[i];
    ushort4 o = make_ushort4(f2bf(v.x), f2bf(v.y), f2bf(v.z), f2bf(v.w));
    reinterpret_cast<ushort4*>(dataB)[i] = o;
}

// ---- prep: W2t[col][k] = adj[k,c] * w_in[c, k-(k>c), h],  col = c*64+h ----
__global__ __launch_bounds__(256) void k_prep_w2t(const float* __restrict__ adj,
                                                  const float* __restrict__ w_in,
                                                  unsigned short* __restrict__ W2t) {
    __shared__ float t[64][65];
    int c  = blockIdx.x >> 2;
    int k0 = (blockIdx.x & 3) * 64;
    int tid = threadIdx.x;
#pragma unroll
    for (int i = 0; i < 16; ++i) {
        int lin = i * 256 + tid;
        int kr = lin >> 6, h = lin & 63;
        int k = k0 + kr;
        float v = 0.0f;
        if (k != c) {
            int m = k - (k > c ? 1 : 0);
            v = adj[k * NV + c] * w_in[((size_t)c * 255 + m) * 64 + h];
        }
        t[kr][h] = v;
    }
    __syncthreads();
#pragma unroll
    for (int i = 0; i < 16; ++i) {
        int lin = i * 256 + tid;
        int h = lin >> 6, kr = lin & 63;
        W2t[((size_t)(c * 64 + h)) * NV + k0 + kr] = f2bf(t[kr][h]);
    }
}

// ---- prep: out0 = adj copy (f32), g[c*64+h] = neurons[h,c]*w_out[c*64+h] ----
__global__ __launch_bounds__(256) void k_misc(const float* __restrict__ adj,
                                              const float* __restrict__ neurons,
                                              const float* __restrict__ w_out,
                                              float* __restrict__ out0,
                                              float* __restrict__ g) {
    int i = blockIdx.x * 256 + threadIdx.x;          // 81920 total
    if (i < NV * NV) {
        out0[i] = adj[i];
    } else {
        int j = i - NV * NV;
        int c = j >> 6, h = j & 63;
        g[j] = neurons[h * NV + c] * w_out[j];
    }
}

// ---- main: 256x256 tile GEMM (4096x256 @ 256x16384) + fused tanh/gate/reduce
// 8 waves (2 rows x 4 cols of 128x64), BK=64, double-buffered, counted vmcnt.
__global__ __launch_bounds__(512, 2) void k_gemm_fused(
        const unsigned short* __restrict__ dataB,   // [4096][256] bf16
        const unsigned short* __restrict__ W2t,     // [16384][256] bf16
        const float* __restrict__ g,                // [16384]
        const float* __restrict__ b_in,             // [16384]
        const float* __restrict__ b_out,            // [256]
        float* __restrict__ out1)                   // [4096][256]
{
    extern __shared__ __align__(16) char lds[];     // 128 KiB: A0,B0,A1,B1 (32K each)
    const int tid  = threadIdx.x;
    const int w    = tid >> 6;
    const int lane = tid & 63;
    const int wr   = w >> 2, wc = w & 3;

    // Bijective XCD swizzle: 1024 blocks, 128 per XCD chunk (16m x 8n -> each
    // XCD's L2 holds full A panel (2MB) + its 8 B columns (1MB)).
    const int orig = (int)blockIdx.x;
    const int swz  = (orig & 7) * 128 + (orig >> 3);
    const int bm0  = (swz & 15) << 8;
    const int bn0  = (swz >> 4) << 8;

    f4v acc[8][4];
#pragma unroll
    for (int mi = 0; mi < 8; ++mi)
#pragma unroll
        for (int ni = 0; ni < 4; ++ni)
            acc[mi][ni] = (f4v){0.f, 0.f, 0.f, 0.f};

    // Staging: per K-tile, A = 256x64 bf16 = 32KB, B same. 512 threads x 16B
    // x 4 rounds covers 32KB. LDS dest LINEAR (global_load_lds constraint);
    // XOR swizzle applied to the GLOBAL source + again on ds_read (rule #21).
    unsigned gA[4], gB[4], lo[4];
#pragma unroll
    for (int t = 0; t < 4; ++t) {
        int lin   = t * 8192 + w * 1024 + lane * 16;   // byte offset in 32KB tile
        int row   = lin >> 7;                          // 128B per row (64 bf16)
        int inner = (lin & 127) ^ ((row & 7) << 4);    // inverse swizzle on source
        lo[t] = (unsigned)(t * 8192 + w * 1024);       // wave-uniform LDS base
        gA[t] = (unsigned)(bm0 + row) * 512u + (unsigned)inner;
        gB[t] = (unsigned)(bn0 + row) * 512u + (unsigned)inner;
    }
    const char* dA = (const char*)dataB;
    const char* dB = (const char*)W2t;

#define STAGE(KT, BUFOFF)                                                     \
    do {                                                                      \
        _Pragma("unroll")                                                     \
        for (int t = 0; t < 4; ++t)                                           \
            gload16(dA + (size_t)(gA[t] + (KT) * 128), lds + (BUFOFF) + lo[t]); \
        _Pragma("unroll")                                                     \
        for (int t = 0; t < 4; ++t)                                           \
            gload16(dB + (size_t)(gB[t] + (KT) * 128), lds + (BUFOFF) + 32768 + lo[t]); \
    } while (0)

    // Prologue: stage tiles 0 and 1 (16 loads in flight per wave).
    STAGE(0, 0);
    STAGE(1, 65536);

#pragma unroll
    for (int kt = 0; kt < 4; ++kt) {
        const int bufo = (kt & 1) ? 65536 : 0;
        if (kt < 3) { asm volatile("s_waitcnt vmcnt(8)" ::: "memory"); }
        else        { asm volatile("s_waitcnt vmcnt(0)" ::: "memory"); }
        __builtin_amdgcn_sched_barrier(0);
        __builtin_amdgcn_s_barrier();   // tile kt fully landed for all waves

#pragma unroll
        for (int kk = 0; kk < 2; ++kk) {
            s8v afr[8], bfr[4];
#pragma unroll
            for (int mi = 0; mi < 8; ++mi) {
                int ml    = wr * 128 + mi * 16 + (lane & 15);
                int inner = (kk * 64 + ((lane >> 4) << 4)) ^ ((ml & 7) << 4);
                afr[mi] = *reinterpret_cast<const s8v*>(lds + bufo + ml * 128 + inner);
            }
#pragma unroll
            for (int ni = 0; ni < 4; ++ni) {
                int nl    = wc * 64 + ni * 16 + (lane & 15);
                int inner = (kk * 64 + ((lane >> 4) << 4)) ^ ((nl & 7) << 4);
                bfr[ni] = *reinterpret_cast<const s8v*>(lds + bufo + 32768 + nl * 128 + inner);
            }
            __builtin_amdgcn_s_setprio(1);
#pragma unroll
            for (int mi = 0; mi < 8; ++mi)
#pragma unroll
                for (int ni = 0; ni < 4; ++ni)
                    acc[mi][ni] = __builtin_amdgcn_mfma_f32_16x16x32_bf16(
                        afr[mi], bfr[ni], acc[mi][ni], 0, 0, 0);
            __builtin_amdgcn_s_setprio(0);
        }

        __builtin_amdgcn_sched_barrier(0);
        __builtin_amdgcn_s_barrier();   // all waves done reading buf -> safe to overwrite
        if (kt == 0) STAGE(2, 0);
        if (kt == 1) STAGE(3, 65536);
    }
#undef STAGE

    // Epilogue: out[n,c] = b_out[c] + sum_h tanh(pre + b_in) * g
    // C/D layout: col = lane&15, row = (lane>>4)*4 + reg   [m89-verified]
    const int cidx = (bn0 >> 6) + wc;                // this wave's channel c
    float gr[4], bi[4];
#pragma unroll
    for (int ni = 0; ni < 4; ++ni) {
        int col = bn0 + wc * 64 + ni * 16 + (lane & 15);
        gr[ni] = g[col];
        bi[ni] = b_in[col];
    }
    const float bo = b_out[cidx];
#pragma unroll
    for (int mi = 0; mi < 8; ++mi) {
#pragma unroll
        for (int r = 0; r < 4; ++r) {
            float s = 0.f;
#pragma unroll
            for (int ni = 0; ni < 4; ++ni)
                s += tanh_fast(acc[mi][ni][r] + bi[ni]) * gr[ni];
            // reduce over the 16 lanes holding this row's 16 columns (x4 ni = 64 h)
            s += __shfl_xor(s, 1);
            s += __shfl_xor(s, 2);
            s += __shfl_xor(s, 4);
            s += __shfl_xor(s, 8);
            if ((lane & 15) == 0) {
                int m = bm0 + wr * 128 + mi * 16 + ((lane >> 4) << 2) + r;
                out1[m * NV + cidx] = s + bo;
            }
        }
    }
}

extern "C" void kernel_launch(void* const* d_in, const int* in_sizes, int n_in,
                              void* d_out, int out_size, void* d_ws, size_t ws_size,
                              hipStream_t stream) {
    const float* data    = (const float*)d_in[0];
    const float* adj     = (const float*)d_in[1];
    const float* neurons = (const float*)d_in[2];
    const float* w_in    = (const float*)d_in[3];
    const float* b_in    = (const float*)d_in[4];
    const float* w_out   = (const float*)d_in[5];
    const float* b_out   = (const float*)d_in[6];

    float* out0 = (float*)d_out;
    float* out1 = out0 + NV * NV;

    unsigned short* dataB = (unsigned short*)d_ws;                       // 2 MiB
    unsigned short* W2t   = (unsigned short*)((char*)d_ws + 2097152);    // 8 MiB
    float*          g     = (float*)((char*)d_ws + 10485760);            // 64 KiB

    hipLaunchKernelGGL(k_prep_data, dim3(1024), dim3(256), 0, stream, data, dataB);
    hipLaunchKernelGGL(k_prep_w2t,  dim3(1024), dim3(256), 0, stream, adj, w_in, W2t);
    hipLaunchKernelGGL(k_misc,      dim3(320),  dim3(256), 0, stream, adj, neurons, w_out, out0, g);
    hipLaunchKernelGGL(k_gemm_fused, dim3(1024), dim3(512), 131072, stream,
                       dataB, W2t, g, b_in, b_out, out1);
}